// Round 7
// baseline (402.654 us; speedup 1.0000x reference)
//
#include <hip/hip_runtime.h>
#include <math.h>

// Problem: bs=8, seq=2048, d_in=d_out=2048, R=8, ctr_out=32, ctr_final=4
// ws layout (floats): A[8*8*2048] | B[8*8*2048]  (B has SCALING folded in)

#define BS 8
#define SEQ 2048
#define DIM 2048
#define RR 8
#define SCALING 2.0f   // 16.0 / R

typedef float vf4 __attribute__((ext_vector_type(4)));

// ---------------------------------------------------------------------------
// Kernel 1: gating MLP + A/B generation. (unchanged — ~6 µs, off critical path)
// ---------------------------------------------------------------------------
__global__ void gate_ab_kernel(const float* __restrict__ ctr,
                               const float* __restrict__ gamma,
                               const float* __restrict__ beta,
                               const float* __restrict__ W1,
                               const float* __restrict__ b1,
                               const float* __restrict__ W2,
                               const float* __restrict__ b2,
                               const float* __restrict__ Wa,
                               const float* __restrict__ Wb,
                               float* __restrict__ A,
                               float* __restrict__ B) {
    __shared__ float z_s[BS][32];
    __shared__ float h_s[BS][60];
    __shared__ float logit_s[BS][4];
    __shared__ float gate_s[BS][4];
    const int tid = threadIdx.x;

    {
        const int b = tid >> 5, i = tid & 31;
        float v = ctr[b * 32 + i];
        float s = v;
        #pragma unroll
        for (int m = 16; m; m >>= 1) s += __shfl_xor(s, m, 64);
        const float mu = s * (1.0f / 32.0f);
        const float d = v - mu;
        float sq = d * d;
        #pragma unroll
        for (int m = 16; m; m >>= 1) sq += __shfl_xor(sq, m, 64);
        const float var = sq * (1.0f / 32.0f);
        z_s[b][i] = d * rsqrtf(var + 1e-5f) * gamma[i] + beta[i];
    }
    __syncthreads();

    for (int idx = tid; idx < BS * 60; idx += 256) {
        const int b = idx / 60, j = idx % 60;
        float acc = b1[j];
        #pragma unroll
        for (int k = 0; k < 32; ++k) acc += z_s[b][k] * W1[j * 32 + k];
        h_s[b][j] = fmaxf(acc, 0.0f);
    }
    __syncthreads();

    if (tid < 32) {
        const int b = tid >> 2, c = tid & 3;
        float acc = b2[c];
        for (int k = 0; k < 60; ++k) acc += h_s[b][k] * W2[c * 60 + k];
        logit_s[b][c] = acc;
    }
    __syncthreads();

    if (tid < 8) {
        float m = logit_s[tid][0];
        #pragma unroll
        for (int c = 1; c < 4; ++c) m = fmaxf(m, logit_s[tid][c]);
        float e[4], s = 0.0f;
        #pragma unroll
        for (int c = 0; c < 4; ++c) { e[c] = expf(logit_s[tid][c] - m); s += e[c]; }
        const float inv = 1.0f / s;
        #pragma unroll
        for (int c = 0; c < 4; ++c) gate_s[tid][c] = e[c] * inv;
    }
    __syncthreads();

    const vf4* __restrict__ Wa4 = (const vf4*)Wa;
    const vf4* __restrict__ Wb4 = (const vf4*)Wb;
    const int total = BS * RR * DIM;   // 131072
    for (int idx = blockIdx.x * 256 + tid; idx < total; idx += gridDim.x * 256) {
        const int b = idx >> 14, rd = idx & 16383;
        const vf4 g = *(const vf4*)gate_s[b];
        const vf4 wa = Wa4[rd];
        A[idx] = g.x * wa.x + g.y * wa.y + g.z * wa.z + g.w * wa.w;
        const vf4 wb = Wb4[rd];
        B[idx] = SCALING * (g.x * wb.x + g.y * wb.y + g.z * wb.z + g.w * wb.w);
    }
}

// ---------------------------------------------------------------------------
// Fused kernel v4 — spill-proof software-pipelined tiles.
// EVIDENCE LOG:
//  - v1 (A,B via LDS, float4 ops): WRITE clean 133 MB, 84 us (phase-serialized).
//  - r1/r5/r6 no-LDS variants: >64 live VGPRs pinned at VGPR_Count=64 ->
//    scratch spill; spill footprint/CU >> L2 -> symmetric extra HBM R+W
//    (r6: +170R/+155W) and ~2.9 TB/s plateau. Root cause was SPILL, not TCC.
// DESIGN:
//  - A and B BOTH staged in LDS (128 KB, 1 block/CU, 512 thr = 8 waves).
//    ONE barrier total.
//  - 1 row/wave/tile, 8 tiles/block (64 rows). Software pipeline: phase-2
//    store loop of tile t also issues x-row loads of tile t+1 -> continuous
//    read+write mixing at HBM (duplex), no inter-block phase luck needed.
//  - Peak live regs ~120 (xcur 32 + xnxt 32 + acc 8 + LDS operands 32 + misc);
//    __launch_bounds__(512,2) caps at 256 VGPRs -> no spill, and 512 thr/CU
//    of scratch (if any) trivially fits L2.
//  - Store loop body: ds_read + FMA + float4 store only (v1-proven pattern).
// ---------------------------------------------------------------------------
__global__ void __launch_bounds__(512, 2)
fused_kernel(const float* __restrict__ x, const float* __restrict__ A,
             const float* __restrict__ B, float* __restrict__ out) {
    __shared__ float Als[RR * DIM];   // 64 KB
    __shared__ float Bls[RR * DIM];   // 64 KB
    const int b     = blockIdx.x >> 5;    // 32 blocks per sample
    const int chunk = blockIdx.x & 31;    // 64 consecutive rows per block
    const int wave  = threadIdx.x >> 6, lane = threadIdx.x & 63;
    const int base  = chunk * 64;
    const int l4    = lane * 4;

    // ---- issue tile-0 x loads immediately (overlap with staging) ----
    float4 xcur[8], xnxt[8];
    {
        const float* __restrict__ xr0 =
            x + ((size_t)(b * SEQ + base + wave)) * DIM;
        #pragma unroll
        for (int j = 0; j < 8; ++j)
            xcur[j] = *(const float4*)&xr0[j * 256 + l4];
    }

    // ---- stage A and B into LDS (once per block) ----
    {
        const float4* __restrict__ srcA = (const float4*)(A + b * (RR * DIM));
        const float4* __restrict__ srcB = (const float4*)(B + b * (RR * DIM));
        float4* dA = (float4*)Als;
        float4* dB = (float4*)Bls;
        #pragma unroll
        for (int k = 0; k < 8; ++k) {
            const int i = k * 512 + threadIdx.x;
            dA[i] = srcA[i];
            dB[i] = srcB[i];
        }
    }
    __syncthreads();   // the only barrier

    for (int t = 0; t < 8; ++t) {
        const int row = base + t * 8 + wave;

        // ---- phase 1: acc[r] = partial dot(x[row], A[r]) ----
        float acc[8];
        #pragma unroll
        for (int r = 0; r < 8; ++r) acc[r] = 0.0f;
        #pragma unroll
        for (int j = 0; j < 8; ++j) {
            const int d = j * 256 + l4;
            float4 a4[8];
            #pragma unroll
            for (int r = 0; r < 8; ++r) a4[r] = *(const float4*)&Als[r * DIM + d];
            #pragma unroll
            for (int r = 0; r < 8; ++r)
                acc[r] += xcur[j].x * a4[r].x + xcur[j].y * a4[r].y +
                          xcur[j].z * a4[r].z + xcur[j].w * a4[r].w;
        }

        // ---- butterfly reduce: every lane gets full xa[8] for this row ----
        float xa[8];
        #pragma unroll
        for (int r = 0; r < 8; ++r) {
            float v = acc[r];
            #pragma unroll
            for (int off = 32; off; off >>= 1) v += __shfl_xor(v, off, 64);
            xa[r] = v;
        }

        // ---- phase 2: store row; interleave x-prefetch of tile t+1 ----
        const float* __restrict__ xn =
            x + ((size_t)(b * SEQ + row + 8)) * DIM;
        float* __restrict__ ob = out + ((size_t)(b * SEQ + row)) * DIM;
        #pragma unroll
        for (int j = 0; j < 8; ++j) {
            const int d = j * 256 + l4;
            if (t < 7) xnxt[j] = *(const float4*)&xn[d];
            float4 b4[8];
            #pragma unroll
            for (int r = 0; r < 8; ++r) b4[r] = *(const float4*)&Bls[r * DIM + d];
            float4 o = {0.0f, 0.0f, 0.0f, 0.0f};
            #pragma unroll
            for (int r = 0; r < 8; ++r) {
                o.x += xa[r] * b4[r].x;
                o.y += xa[r] * b4[r].y;
                o.z += xa[r] * b4[r].z;
                o.w += xa[r] * b4[r].w;
            }
            *(float4*)&ob[d] = o;
        }
        #pragma unroll
        for (int j = 0; j < 8; ++j) xcur[j] = xnxt[j];
    }
}

extern "C" void kernel_launch(void* const* d_in, const int* in_sizes, int n_in,
                              void* d_out, int out_size, void* d_ws, size_t ws_size,
                              hipStream_t stream) {
    const float* x     = (const float*)d_in[0];
    const float* ctr   = (const float*)d_in[1];
    const float* gamma = (const float*)d_in[2];
    const float* beta  = (const float*)d_in[3];
    const float* W1    = (const float*)d_in[4];
    const float* b1    = (const float*)d_in[5];
    const float* W2    = (const float*)d_in[6];
    const float* b2    = (const float*)d_in[7];
    const float* Wa    = (const float*)d_in[8];
    const float* Wb    = (const float*)d_in[9];

    float* ws = (float*)d_ws;
    float* A  = ws;                  // 131072 floats
    float* B  = ws + 131072;         // 131072 floats
    float* out = (float*)d_out;

    gate_ab_kernel<<<128, 256, 0, stream>>>(ctr, gamma, beta, W1, b1, W2, b2,
                                            Wa, Wb, A, B);
    fused_kernel<<<BS * 32, 512, 0, stream>>>(x, A, B, out);
}

// Round 8
// 266.295 us; speedup vs baseline: 1.5121x; 1.5121x over previous
//
#include <hip/hip_runtime.h>
#include <math.h>

// Problem: bs=8, seq=2048, d_in=d_out=2048, R=8, ctr_out=32, ctr_final=4
// ws layout (floats): A[8*8*2048] | B[8*8*2048]  (B has SCALING folded in)

#define BS 8
#define SEQ 2048
#define DIM 2048
#define RR 8
#define SCALING 2.0f   // 16.0 / R

typedef float vf4 __attribute__((ext_vector_type(4)));

// ---------------------------------------------------------------------------
// Kernel 1: gating MLP + A/B generation. (unchanged — ~6 µs, off critical path)
// ---------------------------------------------------------------------------
__global__ void gate_ab_kernel(const float* __restrict__ ctr,
                               const float* __restrict__ gamma,
                               const float* __restrict__ beta,
                               const float* __restrict__ W1,
                               const float* __restrict__ b1,
                               const float* __restrict__ W2,
                               const float* __restrict__ b2,
                               const float* __restrict__ Wa,
                               const float* __restrict__ Wb,
                               float* __restrict__ A,
                               float* __restrict__ B) {
    __shared__ float z_s[BS][32];
    __shared__ float h_s[BS][60];
    __shared__ float logit_s[BS][4];
    __shared__ float gate_s[BS][4];
    const int tid = threadIdx.x;

    {
        const int b = tid >> 5, i = tid & 31;
        float v = ctr[b * 32 + i];
        float s = v;
        #pragma unroll
        for (int m = 16; m; m >>= 1) s += __shfl_xor(s, m, 64);
        const float mu = s * (1.0f / 32.0f);
        const float d = v - mu;
        float sq = d * d;
        #pragma unroll
        for (int m = 16; m; m >>= 1) sq += __shfl_xor(sq, m, 64);
        const float var = sq * (1.0f / 32.0f);
        z_s[b][i] = d * rsqrtf(var + 1e-5f) * gamma[i] + beta[i];
    }
    __syncthreads();

    for (int idx = tid; idx < BS * 60; idx += 256) {
        const int b = idx / 60, j = idx % 60;
        float acc = b1[j];
        #pragma unroll
        for (int k = 0; k < 32; ++k) acc += z_s[b][k] * W1[j * 32 + k];
        h_s[b][j] = fmaxf(acc, 0.0f);
    }
    __syncthreads();

    if (tid < 32) {
        const int b = tid >> 2, c = tid & 3;
        float acc = b2[c];
        for (int k = 0; k < 60; ++k) acc += h_s[b][k] * W2[c * 60 + k];
        logit_s[b][c] = acc;
    }
    __syncthreads();

    if (tid < 8) {
        float m = logit_s[tid][0];
        #pragma unroll
        for (int c = 1; c < 4; ++c) m = fmaxf(m, logit_s[tid][c]);
        float e[4], s = 0.0f;
        #pragma unroll
        for (int c = 0; c < 4; ++c) { e[c] = expf(logit_s[tid][c] - m); s += e[c]; }
        const float inv = 1.0f / s;
        #pragma unroll
        for (int c = 0; c < 4; ++c) gate_s[tid][c] = e[c] * inv;
    }
    __syncthreads();

    const vf4* __restrict__ Wa4 = (const vf4*)Wa;
    const vf4* __restrict__ Wb4 = (const vf4*)Wb;
    const int total = BS * RR * DIM;   // 131072
    for (int idx = blockIdx.x * 256 + tid; idx < total; idx += gridDim.x * 256) {
        const int b = idx >> 14, rd = idx & 16383;
        const vf4 g = *(const vf4*)gate_s[b];
        const vf4 wa = Wa4[rd];
        A[idx] = g.x * wa.x + g.y * wa.y + g.z * wa.z + g.w * wa.w;
        const vf4 wb = Wb4[rd];
        B[idx] = SCALING * (g.x * wb.x + g.y * wb.y + g.z * wb.z + g.w * wb.w);
    }
}

// ---------------------------------------------------------------------------
// Fused kernel v5 — v1's per-wave code verbatim, barriers 3 -> 1.
// EVIDENCE LOG (8 measurements):
//  - v1 (A,B via 64KB LDS restage, 3 barriers): ONLY traffic-clean kernel
//    ever measured (FETCH 71 MB w/ L3 assist, WRITE 133 MB exact), VGPR 64,
//    84 us. Limit = phase-aligned read-burst/write-burst (2.5 TB/s eff).
//  - r1/r5 (no LDS, B-loads between stores): WRITE 556/FETCH 282 — dirty.
//  - r6 (B in 16 regs): WRITE 288/FETCH 305 — dirty (allocator scratch).
//  - r7 (8-deep prefetch, ~130 live regs): FETCH 467 (spill re-reads) — worst.
//  => Any per-wave restructuring beyond v1's register budget triggers
//     scratch traffic. Change ONLY the inter-phase structure.
// DESIGN: stage A into Als and B into Bls ONCE (128 KB LDS, 1 block/CU,
// 512 thr). ONE barrier. Then each wave runs v1's phase 1 (x-read + ds_read A
// + FMA, 1-deep x pipeline), butterfly, v1's phase 2 (ds_read B + FMA +
// float4 stores) with NO further sync: waves de-stagger, so the CU issues
// reads and writes concurrently (duplex) instead of v1's barrier-aligned
// bursts. Per-wave live set identical to v1 -> no spill.
// ---------------------------------------------------------------------------
__global__ void __launch_bounds__(512, 2)
fused_kernel(const float* __restrict__ x, const float* __restrict__ A,
             const float* __restrict__ B, float* __restrict__ out) {
    __shared__ float Als[RR * DIM];   // 64 KB
    __shared__ float Bls[RR * DIM];   // 64 KB
    const int b    = blockIdx.x >> 6;     // 64 blocks per sample
    const int tile = blockIdx.x & 63;     // 32 rows per block
    const int wave = threadIdx.x >> 6, lane = threadIdx.x & 63;

    // ---- stage A and B into LDS (once, the only barrier) ----
    {
        const float4* __restrict__ srcA = (const float4*)(A + b * (RR * DIM));
        const float4* __restrict__ srcB = (const float4*)(B + b * (RR * DIM));
        float4* dA = (float4*)Als;
        float4* dB = (float4*)Bls;
        #pragma unroll
        for (int k = 0; k < 8; ++k) {
            const int i = k * 512 + threadIdx.x;
            dA[i] = srcA[i];
            dB[i] = srcB[i];
        }
    }
    __syncthreads();

    const float* __restrict__ xr =
        x + ((size_t)(b * SEQ + tile * 32 + wave * 4)) * DIM;

    float acc[4][8];
    #pragma unroll
    for (int i = 0; i < 4; ++i)
        #pragma unroll
        for (int r = 0; r < 8; ++r) acc[i][r] = 0.0f;

    // ---- phase 1: xa = x . A^T, x pipelined 1 deep (v1 verbatim) ----
    float4 xcur[4], xnxt[4];
    {
        const int d0 = lane * 4;
        #pragma unroll
        for (int i = 0; i < 4; ++i)
            xcur[i] = *(const float4*)&xr[(size_t)i * DIM + d0];
    }
    #pragma unroll
    for (int j = 0; j < 8; ++j) {
        const int d = j * 256 + lane * 4;
        if (j < 7) {
            #pragma unroll
            for (int i = 0; i < 4; ++i)
                xnxt[i] = *(const float4*)&xr[(size_t)i * DIM + d + 256];
        }
        float4 a4[8];
        #pragma unroll
        for (int r = 0; r < 8; ++r) a4[r] = *(const float4*)&Als[r * DIM + d];
        #pragma unroll
        for (int i = 0; i < 4; ++i) {
            #pragma unroll
            for (int r = 0; r < 8; ++r)
                acc[i][r] += xcur[i].x * a4[r].x + xcur[i].y * a4[r].y +
                             xcur[i].z * a4[r].z + xcur[i].w * a4[r].w;
        }
        #pragma unroll
        for (int i = 0; i < 4; ++i) xcur[i] = xnxt[i];
    }

    // butterfly reduce across 64 lanes -> every lane holds xa[i][r]
    float xa[4][8];
    #pragma unroll
    for (int i = 0; i < 4; ++i) {
        #pragma unroll
        for (int r = 0; r < 8; ++r) {
            float v = acc[i][r];
            #pragma unroll
            for (int off = 32; off; off >>= 1) v += __shfl_xor(v, off, 64);
            xa[i][r] = v;
        }
    }

    // ---- phase 2: out = xa . B (v1 verbatim, reading Bls; no barrier) ----
    float* __restrict__ ob =
        out + ((size_t)(b * SEQ + tile * 32 + wave * 4)) * DIM;
    #pragma unroll
    for (int j = 0; j < 8; ++j) {
        const int o = j * 256 + lane * 4;
        float4 b4[8];
        #pragma unroll
        for (int r = 0; r < 8; ++r) b4[r] = *(const float4*)&Bls[r * DIM + o];
        #pragma unroll
        for (int i = 0; i < 4; ++i) {
            float4 v = {0.0f, 0.0f, 0.0f, 0.0f};
            #pragma unroll
            for (int r = 0; r < 8; ++r) {
                v.x += xa[i][r] * b4[r].x;
                v.y += xa[i][r] * b4[r].y;
                v.z += xa[i][r] * b4[r].z;
                v.w += xa[i][r] * b4[r].w;
            }
            *(float4*)&ob[(size_t)i * DIM + o] = v;
        }
    }
}

extern "C" void kernel_launch(void* const* d_in, const int* in_sizes, int n_in,
                              void* d_out, int out_size, void* d_ws, size_t ws_size,
                              hipStream_t stream) {
    const float* x     = (const float*)d_in[0];
    const float* ctr   = (const float*)d_in[1];
    const float* gamma = (const float*)d_in[2];
    const float* beta  = (const float*)d_in[3];
    const float* W1    = (const float*)d_in[4];
    const float* b1    = (const float*)d_in[5];
    const float* W2    = (const float*)d_in[6];
    const float* b2    = (const float*)d_in[7];
    const float* Wa    = (const float*)d_in[8];
    const float* Wb    = (const float*)d_in[9];

    float* ws = (float*)d_ws;
    float* A  = ws;                  // 131072 floats
    float* B  = ws + 131072;         // 131072 floats
    float* out = (float*)d_out;

    gate_ab_kernel<<<128, 256, 0, stream>>>(ctr, gamma, beta, W1, b1, W2, b2,
                                            Wa, Wb, A, B);
    fused_kernel<<<BS * 64, 512, 0, stream>>>(x, A, B, out);
}